// Round 10
// baseline (58.573 us; speedup 1.0000x reference)
//
#include <hip/hip_runtime.h>

#define BB 8
#define CC 512
#define NN 2048
#define SEM 32
#define BN_EPS 1e-5f
#define LOG2E 1.4426950408889634f

typedef float floatx4 __attribute__((ext_vector_type(4)));

// ---------------- K1: x pass -> atomic-accumulate gx/tx/px and avg ----------------
// grid = 1024 blocks = (b:8, g:32, q:4). Block: 16 channels x 512-px quarter.
// Thread: one float2 pixel-pair across 16 channels (coalesced 512B/wave loads).
__global__ __launch_bounds__(256) void k1(const float* __restrict__ x,
    const float* __restrict__ gw, const float* __restrict__ tw, const float* __restrict__ pw,
    float* __restrict__ gxa, float* __restrict__ txa, float* __restrict__ pxa,
    float* __restrict__ avg)
{
    int tid = threadIdx.x;
    int lane = tid & 63;
    int blk = blockIdx.x;
    int q = blk & 3;
    int g = (blk >> 2) & 31;
    int b = blk >> 7;
    int c0 = g * 16;

    const float2* xp = reinterpret_cast<const float2*>(x)
                     + (size_t)(b * CC + c0) * (NN / 2) + q * 256 + tid;

    float2 ag = {0,0}, at_ = {0,0}, ap = {0,0};
    float s[16];
    #pragma unroll
    for (int c = 0; c < 16; ++c) {
        float2 v = xp[(size_t)c * (NN / 2)];
        float wg = gw[c0 + c], wt = tw[c0 + c], wp = pw[c0 + c];
        ag.x  = fmaf(wg, v.x, ag.x);  ag.y  = fmaf(wg, v.y, ag.y);
        at_.x = fmaf(wt, v.x, at_.x); at_.y = fmaf(wt, v.y, at_.y);
        ap.x  = fmaf(wp, v.x, ap.x);  ap.y  = fmaf(wp, v.y, ap.y);
        s[c] = v.x + v.y;
    }

    int p = b * NN + q * 512 + tid * 2;
    atomicAdd(&gxa[p],     ag.x);  atomicAdd(&gxa[p + 1], ag.y);
    atomicAdd(&txa[p],     at_.x); atomicAdd(&txa[p + 1], at_.y);
    atomicAdd(&pxa[p],     ap.x);  atomicAdd(&pxa[p + 1], ap.y);

    // ILP-interleaved wave reduce (6 rounds x 16 independent chains)
    #pragma unroll
    for (int o = 32; o > 0; o >>= 1) {
        #pragma unroll
        for (int c = 0; c < 16; ++c) s[c] += __shfl_down(s[c], o);
    }
    if (lane == 0) {
        #pragma unroll
        for (int c = 0; c < 16; ++c)
            atomicAdd(&avg[b * CC + c0 + c], s[c]);
    }
}

// ---------------- K3: rank-1 softmax (exp2, no-max) + SE/affine ----------------
// grid = 1024 + 8. Blocks [0,1024): 16 rows each (4/wave). Blocks [1024,1032): SE.
// gx/tx/px/avg arrive RAW (bias-free sums); biases applied here / folded into Dc.
__global__ __launch_bounds__(256) void k3(
    const float* __restrict__ gx, const float* __restrict__ tx,
    const float* __restrict__ px, const float* __restrict__ avg,
    const float* __restrict__ gb, const float* __restrict__ tb, const float* __restrict__ pb,
    const float* __restrict__ se1w, const float* __restrict__ se1b,
    const float* __restrict__ se2w, const float* __restrict__ se2b,
    const float* __restrict__ Ww, const float* __restrict__ Wb,
    const float* __restrict__ gamma, const float* __restrict__ beta,
    const float* __restrict__ mean, const float* __restrict__ var,
    float* __restrict__ y, float* __restrict__ Ac, float* __restrict__ Dc)
{
    __shared__ float smem[4096];   // 16 KB
    int tid = threadIdx.x;

    if (blockIdx.x >= 1024) {
        // ---- SE / affine for sample b ----
        int b = blockIdx.x - 1024;
        float* sA = smem;          // 512
        float* sP = smem + 512;    // 32*8
        float* sM = smem + 768;    // 32
        for (int c = tid; c < CC; c += 256)
            sA[c] = avg[b * CC + c] * (1.0f / NN);
        __syncthreads();
        {
            int m = tid >> 3, sub = tid & 7;
            const float* w1 = se1w + m * CC + sub * 64;
            const float* a1 = sA + sub * 64;
            float ssum = 0.f;
            #pragma unroll
            for (int k = 0; k < 64; ++k) ssum = fmaf(a1[k], w1[k], ssum);
            sP[m * 8 + sub] = ssum;
        }
        __syncthreads();
        if (tid < SEM) {
            float t = 0.f;
            #pragma unroll
            for (int k = 0; k < 8; ++k) t += sP[tid * 8 + k];
            sM[tid] = fmaxf(t + se1b[tid], 0.f);
        }
        __syncthreads();
        float gbv = gb[0];
        for (int c = tid; c < CC; c += 256) {
            float s2 = 0.f;
            #pragma unroll
            for (int m = 0; m < SEM; ++m) s2 = fmaf(sM[m], se2w[c * SEM + m], s2);
            s2 += se2b[c];
            float wcw = 1.f / (1.f + __expf(-s2));
            float inv = gamma[c] * rsqrtf(var[c] + BN_EPS);
            float A = wcw * Ww[c] * inv;
            Ac[b * CC + c] = A;
            Dc[b * CC + c] = wcw * ((Wb[c] - mean[c]) * inv + beta[c]) + A * gbv;
        }
        return;
    }

    // ---- softmax path ----
    float* spx = smem;           // 2048
    float* sgx = smem + 2048;    // 2048
    int b  = blockIdx.x >> 7;
    int i0 = (blockIdx.x & 127) << 4;
    float pbv = pb[0], tbv = tb[0];
    {
        const float4* pxr = reinterpret_cast<const float4*>(px + (size_t)b * NN);
        const float4* gxr = reinterpret_cast<const float4*>(gx + (size_t)b * NN);
        float4* spx4 = reinterpret_cast<float4*>(spx);
        float4* sgx4 = reinterpret_cast<float4*>(sgx);
        #pragma unroll
        for (int w = 0; w < 2; ++w) {
            int idx = w * 256 + tid;
            float4 pv = pxr[idx];
            pv.x += pbv; pv.y += pbv; pv.z += pbv; pv.w += pbv;
            spx4[idx] = pv;
            sgx4[idx] = gxr[idx];
        }
    }
    __syncthreads();

    int wave = tid >> 6, lane = tid & 63;
    int r0 = i0 + wave * 4;
    float t0 = (tx[b * NN + r0 + 0] + tbv) * LOG2E;
    float t1 = (tx[b * NN + r0 + 1] + tbv) * LOG2E;
    float t2 = (tx[b * NN + r0 + 2] + tbv) * LOG2E;
    float t3 = (tx[b * NN + r0 + 3] + tbv) * LOG2E;
    float s0 = 0.f, g0 = 0.f, s1 = 0.f, g1 = 0.f;
    float s2 = 0.f, g2 = 0.f, s3 = 0.f, g3 = 0.f;
    const float2* spx2 = reinterpret_cast<const float2*>(spx);
    const float2* sgx2 = reinterpret_cast<const float2*>(sgx);
    #pragma unroll 4
    for (int it = 0; it < 16; ++it) {
        int jj = it * 64 + lane;
        float2 xv = spx2[jj];
        float2 gv = sgx2[jj];
        float e0a = exp2f(fminf(t0 * xv.x, 115.f)), e0b = exp2f(fminf(t0 * xv.y, 115.f));
        float e1a = exp2f(fminf(t1 * xv.x, 115.f)), e1b = exp2f(fminf(t1 * xv.y, 115.f));
        float e2a = exp2f(fminf(t2 * xv.x, 115.f)), e2b = exp2f(fminf(t2 * xv.y, 115.f));
        float e3a = exp2f(fminf(t3 * xv.x, 115.f)), e3b = exp2f(fminf(t3 * xv.y, 115.f));
        s0 += e0a + e0b; g0 = fmaf(e0a, gv.x, fmaf(e0b, gv.y, g0));
        s1 += e1a + e1b; g1 = fmaf(e1a, gv.x, fmaf(e1b, gv.y, g1));
        s2 += e2a + e2b; g2 = fmaf(e2a, gv.x, fmaf(e2b, gv.y, g2));
        s3 += e3a + e3b; g3 = fmaf(e3a, gv.x, fmaf(e3b, gv.y, g3));
    }
    for (int o = 32; o > 0; o >>= 1) {
        s0 += __shfl_down(s0, o); g0 += __shfl_down(g0, o);
        s1 += __shfl_down(s1, o); g1 += __shfl_down(g1, o);
        s2 += __shfl_down(s2, o); g2 += __shfl_down(g2, o);
        s3 += __shfl_down(s3, o); g3 += __shfl_down(g3, o);
    }
    if (lane == 0) {
        y[b * NN + r0 + 0] = g0 / s0;
        y[b * NN + r0 + 1] = g1 / s1;
        y[b * NN + r0 + 2] = g2 / s2;
        y[b * NN + r0 + 3] = g3 / s3;
    }
}

// ---------------- K4: epilogue out = A*y + D + x (nontemporal stores) ----------------
__global__ __launch_bounds__(256) void k4(
    const float* __restrict__ x, const float* __restrict__ y,
    const float* __restrict__ Ac, const float* __restrict__ Dc,
    float* __restrict__ out)
{
    int bc = blockIdx.x;
    int b = bc >> 9;
    float a = Ac[bc], d = Dc[bc];
    const float4* x4 = reinterpret_cast<const float4*>(x) + (size_t)bc * (NN / 4);
    const float4* y4 = reinterpret_cast<const float4*>(y) + (size_t)b * (NN / 4);
    floatx4* o4 = reinterpret_cast<floatx4*>(out) + (size_t)bc * (NN / 4);
    int tid = threadIdx.x;
    #pragma unroll
    for (int k = 0; k < 2; ++k) {
        int idx = k * 256 + tid;
        float4 xv = x4[idx], yv = y4[idx];
        floatx4 ov;
        ov.x = fmaf(a, yv.x, d) + xv.x;
        ov.y = fmaf(a, yv.y, d) + xv.y;
        ov.z = fmaf(a, yv.z, d) + xv.z;
        ov.w = fmaf(a, yv.w, d) + xv.w;
        __builtin_nontemporal_store(ov, &o4[idx]);
    }
}

extern "C" void kernel_launch(void* const* d_in, const int* in_sizes, int n_in,
                              void* d_out, int out_size, void* d_ws, size_t ws_size,
                              hipStream_t stream) {
    const float* x    = (const float*)d_in[0];
    const float* gw   = (const float*)d_in[1];
    const float* gb   = (const float*)d_in[2];
    const float* tw   = (const float*)d_in[3];
    const float* tb   = (const float*)d_in[4];
    const float* pw   = (const float*)d_in[5];
    const float* pb   = (const float*)d_in[6];
    const float* Ww   = (const float*)d_in[7];
    const float* Wb   = (const float*)d_in[8];
    const float* gam  = (const float*)d_in[9];
    const float* bet  = (const float*)d_in[10];
    const float* mu   = (const float*)d_in[11];
    const float* var  = (const float*)d_in[12];
    const float* se1w = (const float*)d_in[13];
    const float* se1b = (const float*)d_in[14];
    const float* se2w = (const float*)d_in[15];
    const float* se2b = (const float*)d_in[16];

    float* ws  = (float*)d_ws;
    float* gxa = ws; ws += BB * NN;
    float* txa = ws; ws += BB * NN;
    float* pxa = ws; ws += BB * NN;
    float* avg = ws; ws += BB * CC;
    float* y   = ws; ws += BB * NN;
    float* Ac  = ws; ws += BB * CC;
    float* Dc  = ws; ws += BB * CC;
    float* out = (float*)d_out;

    // zero the atomic accumulators (graph-capturable memset node)
    size_t zbytes = (size_t)(3 * BB * NN + BB * CC) * sizeof(float);
    (void)hipMemsetAsync((void*)gxa, 0, zbytes, stream);

    k1<<<1024, 256, 0, stream>>>(x, gw, tw, pw, gxa, txa, pxa, avg);
    k3<<<1024 + BB, 256, 0, stream>>>(gxa, txa, pxa, avg, gb, tb, pb,
                                      se1w, se1b, se2w, se2b,
                                      Ww, Wb, gam, bet, mu, var, y, Ac, Dc);
    k4<<<BB * CC, 256, 0, stream>>>(x, y, Ac, Dc, out);
}

// Round 11
// 43.906 us; speedup vs baseline: 1.3340x; 1.3340x over previous
//
#include <hip/hip_runtime.h>

#define BB 8
#define CC 512
#define NN 2048
#define SEM 32
#define BN_EPS 1e-5f
#define LOG2E 1.4426950408889634f

#define NCC 16                 // channels per group
#define NG (CC / NCC)          // 32 groups
#define KARR (NG * BB * NN)    // 524288 floats per projection partial array

typedef float floatx4 __attribute__((ext_vector_type(4)));

// ---------------- K1: x pass -> pp partials + avg partials ----------------
// grid = 1024 blocks = (b:8, g:32, q:4). Block: 16 channels x 512-px quarter.
// 4 blocks/CU; thread preloads 16 float2 (fully coalesced 512B wave-loads).
__global__ __launch_bounds__(256, 4) void k1(const float* __restrict__ x,
    const float* __restrict__ gw, const float* __restrict__ tw, const float* __restrict__ pw,
    float* __restrict__ pp, float* __restrict__ avgp)
{
    int tid = threadIdx.x;
    int wave = tid >> 6, lane = tid & 63;
    int blk = blockIdx.x;
    int q = blk & 3;
    int g = (blk >> 2) & (NG - 1);
    int b = blk >> 7;
    int c0 = g * NCC;

    const float2* xp = reinterpret_cast<const float2*>(x)
                     + (size_t)(b * CC + c0) * (NN / 2) + q * 256 + tid;

    float2 v[NCC];
    #pragma unroll
    for (int c = 0; c < NCC; ++c)
        v[c] = xp[(size_t)c * (NN / 2)];

    float2 ag = {0,0}, at_ = {0,0}, ap = {0,0};
    float s[NCC];
    #pragma unroll
    for (int c = 0; c < NCC; ++c) {
        float wg = gw[c0 + c], wt = tw[c0 + c], wp = pw[c0 + c];
        ag.x  = fmaf(wg, v[c].x, ag.x);  ag.y  = fmaf(wg, v[c].y, ag.y);
        at_.x = fmaf(wt, v[c].x, at_.x); at_.y = fmaf(wt, v[c].y, at_.y);
        ap.x  = fmaf(wp, v[c].x, ap.x);  ap.y  = fmaf(wp, v[c].y, ap.y);
        s[c] = v[c].x + v[c].y;
    }

    // pp[k][g][b][p] (float2 view): base2 = (g*BB+b)*1024 + q*256 + tid
    size_t base2 = (size_t)(g * BB + b) * (NN / 2) + q * 256 + tid;
    float2* pp2 = reinterpret_cast<float2*>(pp);
    pp2[base2]            = ag;
    pp2[base2 + KARR / 2] = at_;
    pp2[base2 + KARR]     = ap;

    // ILP-interleaved wave reduce (6 rounds x 16 independent chains)
    #pragma unroll
    for (int o = 32; o > 0; o >>= 1) {
        #pragma unroll
        for (int c = 0; c < NCC; ++c) s[c] += __shfl_down(s[c], o);
    }
    if (lane == 0) {
        #pragma unroll
        for (int c = 0; c < NCC; ++c)
            avgp[(size_t)(b * CC + c0 + c) * 16 + q * 4 + wave] = s[c];
    }
}

// ---------------- K2: finalize gx/tx/px (blocks 0..191) || SE/affine (192..199) ----------------
// finalize: blk = b*24 + k*8 + oct; thread = 1 pixel, 32 coalesced loads.
__global__ __launch_bounds__(256) void k2(
    const float* __restrict__ pp, const float* __restrict__ avgp,
    const float* __restrict__ gb, const float* __restrict__ tb, const float* __restrict__ pb,
    const float* __restrict__ se1w, const float* __restrict__ se1b,
    const float* __restrict__ se2w, const float* __restrict__ se2b,
    const float* __restrict__ Ww, const float* __restrict__ Wb,
    const float* __restrict__ gamma, const float* __restrict__ beta,
    const float* __restrict__ mean, const float* __restrict__ var,
    float* __restrict__ gx, float* __restrict__ tx, float* __restrict__ px,
    float* __restrict__ Ac, float* __restrict__ Dc)
{
    int tid = threadIdx.x;
    if (blockIdx.x < 192) {
        int oct = blockIdx.x & 7;
        int g3  = blockIdx.x >> 3;     // 0..23
        int k   = g3 % 3;
        int b   = g3 / 3;
        int p   = oct * 256 + tid;
        const float* base = pp + (size_t)k * KARR + (size_t)b * NN + p;
        float v = 0.f;
        #pragma unroll
        for (int g = 0; g < NG; ++g)
            v += base[(size_t)g * BB * NN];
        int o = b * NN + p;
        if (k == 0)      gx[o] = v;              // gb folded into Dc
        else if (k == 1) tx[o] = v + tb[0];
        else             px[o] = v + pb[0];
        return;
    }

    // ---- SE / affine for sample b ----
    __shared__ float smem[1024];
    int b = blockIdx.x - 192;
    float* sA = smem;          // 512
    float* sP = smem + 512;    // 32*8
    float* sM = smem + 768;    // 32
    for (int c = tid; c < CC; c += 256) {
        const float* apt = avgp + (size_t)(b * CC + c) * 16;
        float ssum = 0.f;
        #pragma unroll
        for (int k = 0; k < 16; ++k) ssum += apt[k];
        sA[c] = ssum * (1.0f / NN);
    }
    __syncthreads();
    {
        int m = tid >> 3, sub = tid & 7;
        const float* w1 = se1w + m * CC + sub * 64;
        const float* a1 = sA + sub * 64;
        float ssum = 0.f;
        #pragma unroll
        for (int k = 0; k < 64; ++k) ssum = fmaf(a1[k], w1[k], ssum);
        sP[m * 8 + sub] = ssum;
    }
    __syncthreads();
    if (tid < SEM) {
        float t = 0.f;
        #pragma unroll
        for (int k = 0; k < 8; ++k) t += sP[tid * 8 + k];
        sM[tid] = fmaxf(t + se1b[tid], 0.f);
    }
    __syncthreads();
    float gbv = gb[0];
    for (int c = tid; c < CC; c += 256) {
        float s2 = 0.f;
        #pragma unroll
        for (int m = 0; m < SEM; ++m) s2 = fmaf(sM[m], se2w[c * SEM + m], s2);
        s2 += se2b[c];
        float wcw = 1.f / (1.f + __expf(-s2));
        float inv = gamma[c] * rsqrtf(var[c] + BN_EPS);
        float A = wcw * Ww[c] * inv;
        Ac[b * CC + c] = A;
        Dc[b * CC + c] = wcw * ((Wb[c] - mean[c]) * inv + beta[c]) + A * gbv;
    }
}

// ---------------- K3: rank-1 softmax (exp2, no-max) ----------------
// grid = 1024 blocks: 16 rows each, 4 per wave. Biases already applied.
__global__ __launch_bounds__(256) void k3(
    const float* __restrict__ gx, const float* __restrict__ tx,
    const float* __restrict__ px, float* __restrict__ y)
{
    __shared__ float smem[4096];
    int tid = threadIdx.x;
    float* spx = smem;           // 2048
    float* sgx = smem + 2048;    // 2048
    int b  = blockIdx.x >> 7;
    int i0 = (blockIdx.x & 127) << 4;
    {
        const float4* pxr = reinterpret_cast<const float4*>(px + (size_t)b * NN);
        const float4* gxr = reinterpret_cast<const float4*>(gx + (size_t)b * NN);
        float4* spx4 = reinterpret_cast<float4*>(spx);
        float4* sgx4 = reinterpret_cast<float4*>(sgx);
        #pragma unroll
        for (int w = 0; w < 2; ++w) {
            int idx = w * 256 + tid;
            spx4[idx] = pxr[idx];
            sgx4[idx] = gxr[idx];
        }
    }
    __syncthreads();

    int wave = tid >> 6, lane = tid & 63;
    int r0 = i0 + wave * 4;
    float t0 = tx[b * NN + r0 + 0] * LOG2E;
    float t1 = tx[b * NN + r0 + 1] * LOG2E;
    float t2 = tx[b * NN + r0 + 2] * LOG2E;
    float t3 = tx[b * NN + r0 + 3] * LOG2E;
    float s0 = 0.f, g0 = 0.f, s1 = 0.f, g1 = 0.f;
    float s2 = 0.f, g2 = 0.f, s3 = 0.f, g3 = 0.f;
    const float2* spx2 = reinterpret_cast<const float2*>(spx);
    const float2* sgx2 = reinterpret_cast<const float2*>(sgx);
    #pragma unroll 4
    for (int it = 0; it < 16; ++it) {
        int jj = it * 64 + lane;
        float2 xv = spx2[jj];
        float2 gv = sgx2[jj];
        float e0a = exp2f(fminf(t0 * xv.x, 115.f)), e0b = exp2f(fminf(t0 * xv.y, 115.f));
        float e1a = exp2f(fminf(t1 * xv.x, 115.f)), e1b = exp2f(fminf(t1 * xv.y, 115.f));
        float e2a = exp2f(fminf(t2 * xv.x, 115.f)), e2b = exp2f(fminf(t2 * xv.y, 115.f));
        float e3a = exp2f(fminf(t3 * xv.x, 115.f)), e3b = exp2f(fminf(t3 * xv.y, 115.f));
        s0 += e0a + e0b; g0 = fmaf(e0a, gv.x, fmaf(e0b, gv.y, g0));
        s1 += e1a + e1b; g1 = fmaf(e1a, gv.x, fmaf(e1b, gv.y, g1));
        s2 += e2a + e2b; g2 = fmaf(e2a, gv.x, fmaf(e2b, gv.y, g2));
        s3 += e3a + e3b; g3 = fmaf(e3a, gv.x, fmaf(e3b, gv.y, g3));
    }
    for (int o = 32; o > 0; o >>= 1) {
        s0 += __shfl_down(s0, o); g0 += __shfl_down(g0, o);
        s1 += __shfl_down(s1, o); g1 += __shfl_down(g1, o);
        s2 += __shfl_down(s2, o); g2 += __shfl_down(g2, o);
        s3 += __shfl_down(s3, o); g3 += __shfl_down(g3, o);
    }
    if (lane == 0) {
        y[b * NN + r0 + 0] = g0 / s0;
        y[b * NN + r0 + 1] = g1 / s1;
        y[b * NN + r0 + 2] = g2 / s2;
        y[b * NN + r0 + 3] = g3 / s3;
    }
}

// ---------------- K4: epilogue out = A*y + D + x (nontemporal stores) ----------------
__global__ __launch_bounds__(256) void k4(
    const float* __restrict__ x, const float* __restrict__ y,
    const float* __restrict__ Ac, const float* __restrict__ Dc,
    float* __restrict__ out)
{
    int bc = blockIdx.x;
    int b = bc >> 9;
    float a = Ac[bc], d = Dc[bc];
    const float4* x4 = reinterpret_cast<const float4*>(x) + (size_t)bc * (NN / 4);
    const float4* y4 = reinterpret_cast<const float4*>(y) + (size_t)b * (NN / 4);
    floatx4* o4 = reinterpret_cast<floatx4*>(out) + (size_t)bc * (NN / 4);
    int tid = threadIdx.x;
    #pragma unroll
    for (int k = 0; k < 2; ++k) {
        int idx = k * 256 + tid;
        float4 xv = x4[idx], yv = y4[idx];
        floatx4 ov;
        ov.x = fmaf(a, yv.x, d) + xv.x;
        ov.y = fmaf(a, yv.y, d) + xv.y;
        ov.z = fmaf(a, yv.z, d) + xv.z;
        ov.w = fmaf(a, yv.w, d) + xv.w;
        __builtin_nontemporal_store(ov, &o4[idx]);
    }
}

extern "C" void kernel_launch(void* const* d_in, const int* in_sizes, int n_in,
                              void* d_out, int out_size, void* d_ws, size_t ws_size,
                              hipStream_t stream) {
    const float* x    = (const float*)d_in[0];
    const float* gw   = (const float*)d_in[1];
    const float* gb   = (const float*)d_in[2];
    const float* tw   = (const float*)d_in[3];
    const float* tb   = (const float*)d_in[4];
    const float* pw   = (const float*)d_in[5];
    const float* pb   = (const float*)d_in[6];
    const float* Ww   = (const float*)d_in[7];
    const float* Wb   = (const float*)d_in[8];
    const float* gam  = (const float*)d_in[9];
    const float* bet  = (const float*)d_in[10];
    const float* mu   = (const float*)d_in[11];
    const float* var  = (const float*)d_in[12];
    const float* se1w = (const float*)d_in[13];
    const float* se1b = (const float*)d_in[14];
    const float* se2w = (const float*)d_in[15];
    const float* se2b = (const float*)d_in[16];

    float* ws   = (float*)d_ws;
    float* pp   = ws; ws += 3 * (size_t)KARR;
    float* avgp = ws; ws += BB * CC * 16;
    float* gx   = ws; ws += BB * NN;
    float* tx   = ws; ws += BB * NN;
    float* px   = ws; ws += BB * NN;
    float* y    = ws; ws += BB * NN;
    float* Ac   = ws; ws += BB * CC;
    float* Dc   = ws; ws += BB * CC;
    float* out  = (float*)d_out;

    k1<<<1024, 256, 0, stream>>>(x, gw, tw, pw, pp, avgp);
    k2<<<200, 256, 0, stream>>>(pp, avgp, gb, tb, pb, se1w, se1b, se2w, se2b,
                                Ww, Wb, gam, bet, mu, var, gx, tx, px, Ac, Dc);
    k3<<<1024, 256, 0, stream>>>(gx, tx, px, y);
    k4<<<BB * CC, 256, 0, stream>>>(x, y, Ac, Dc, out);
}

// Round 12
// 43.279 us; speedup vs baseline: 1.3534x; 1.0145x over previous
//
#include <hip/hip_runtime.h>

#define BB 8
#define CC 512
#define NN 2048
#define SEM 32
#define BN_EPS 1e-5f
#define LOG2E 1.4426950408889634f

#define NCC 8                  // channels per group in K1
#define NG (CC / NCC)          // 64 groups
#define KARR (NG * BB * NN)    // 1048576 floats per projection partial array

// ---------------- K1: x pass -> pp partials + avg partials ----------------
// grid = 1024 blocks = (b:8, g:64, h:2). Block: 8 channels x 1024-px half-row.
// float4 loads (16B/lane, 1KB/wave-instruction); 4 blocks/CU.
__global__ __launch_bounds__(256, 4) void k1(const float* __restrict__ x,
    const float* __restrict__ gw, const float* __restrict__ tw, const float* __restrict__ pw,
    float* __restrict__ pp, float* __restrict__ avgp)
{
    int tid = threadIdx.x;
    int wave = tid >> 6, lane = tid & 63;
    int blk = blockIdx.x;
    int h = blk & 1;
    int g = (blk >> 1) & (NG - 1);
    int b = blk >> 7;
    int c0 = g * NCC;

    const float4* xp = reinterpret_cast<const float4*>(x)
                     + (size_t)(b * CC + c0) * (NN / 4) + h * 256 + tid;

    float4 v[NCC];
    #pragma unroll
    for (int c = 0; c < NCC; ++c)
        v[c] = xp[c * (NN / 4)];

    float4 ag = {0,0,0,0}, at_ = {0,0,0,0}, ap = {0,0,0,0};
    float s[NCC];
    #pragma unroll
    for (int c = 0; c < NCC; ++c) {
        float wg = gw[c0 + c], wt = tw[c0 + c], wp = pw[c0 + c];
        ag.x  = fmaf(wg, v[c].x, ag.x);  ag.y  = fmaf(wg, v[c].y, ag.y);
        ag.z  = fmaf(wg, v[c].z, ag.z);  ag.w  = fmaf(wg, v[c].w, ag.w);
        at_.x = fmaf(wt, v[c].x, at_.x); at_.y = fmaf(wt, v[c].y, at_.y);
        at_.z = fmaf(wt, v[c].z, at_.z); at_.w = fmaf(wt, v[c].w, at_.w);
        ap.x  = fmaf(wp, v[c].x, ap.x);  ap.y  = fmaf(wp, v[c].y, ap.y);
        ap.z  = fmaf(wp, v[c].z, ap.z);  ap.w  = fmaf(wp, v[c].w, ap.w);
        s[c] = (v[c].x + v[c].y) + (v[c].z + v[c].w);
    }

    // pp[k][g][b][px], float4 view: stride KARR/4 float4s between the 3 arrays
    size_t base4 = (size_t)(g * BB + b) * (NN / 4) + h * 256 + tid;
    float4* pp4 = reinterpret_cast<float4*>(pp);
    pp4[base4]                = ag;
    pp4[base4 + KARR / 4]     = at_;
    pp4[base4 + KARR / 2]     = ap;

    // ILP-interleaved wave reduce (6 rounds x 8 independent chains)
    #pragma unroll
    for (int o = 32; o > 0; o >>= 1) {
        #pragma unroll
        for (int c = 0; c < NCC; ++c) s[c] += __shfl_down(s[c], o);
    }
    if (lane == 0) {
        #pragma unroll
        for (int c = 0; c < NCC; ++c)
            avgp[(size_t)(b * CC + c0 + c) * 8 + h * 4 + wave] = s[c];
    }
}

// ---------------- K2: finalize gx/tx/px (blocks 0..191) || SE/affine (192..199) ----------------
__global__ __launch_bounds__(256) void k2(
    const float* __restrict__ pp, const float* __restrict__ avgp,
    const float* __restrict__ gb, const float* __restrict__ tb, const float* __restrict__ pb,
    const float* __restrict__ se1w, const float* __restrict__ se1b,
    const float* __restrict__ se2w, const float* __restrict__ se2b,
    const float* __restrict__ Ww, const float* __restrict__ Wb,
    const float* __restrict__ gamma, const float* __restrict__ beta,
    const float* __restrict__ mean, const float* __restrict__ var,
    float* __restrict__ gx, float* __restrict__ tx, float* __restrict__ px,
    float* __restrict__ Ac, float* __restrict__ Dc)
{
    int tid = threadIdx.x;
    if (blockIdx.x < 192) {
        int oct = blockIdx.x & 7;
        int g3  = blockIdx.x >> 3;     // 0..23
        int k   = g3 % 3;
        int b   = g3 / 3;
        int p   = oct * 256 + tid;
        const float* base = pp + (size_t)k * KARR + (size_t)b * NN + p;
        float v = 0.f;
        #pragma unroll 16
        for (int g = 0; g < NG; ++g)
            v += base[(size_t)g * BB * NN];
        int o = b * NN + p;
        if (k == 0)      gx[o] = v;              // gb folded into Dc
        else if (k == 1) tx[o] = v + tb[0];
        else             px[o] = v + pb[0];
        return;
    }

    // ---- SE / affine for sample b ----
    __shared__ float smem[1024];
    int b = blockIdx.x - 192;
    float* sA = smem;          // 512
    float* sP = smem + 512;    // 32*8
    float* sM = smem + 768;    // 32
    for (int c = tid; c < CC; c += 256) {
        const float* apt = avgp + (size_t)(b * CC + c) * 8;
        float ssum = 0.f;
        #pragma unroll
        for (int k = 0; k < 8; ++k) ssum += apt[k];
        sA[c] = ssum * (1.0f / NN);
    }
    __syncthreads();
    {
        int m = tid >> 3, sub = tid & 7;
        const float* w1 = se1w + m * CC + sub * 64;
        const float* a1 = sA + sub * 64;
        float ssum = 0.f;
        #pragma unroll
        for (int k = 0; k < 64; ++k) ssum = fmaf(a1[k], w1[k], ssum);
        sP[m * 8 + sub] = ssum;
    }
    __syncthreads();
    if (tid < SEM) {
        float t = 0.f;
        #pragma unroll
        for (int k = 0; k < 8; ++k) t += sP[tid * 8 + k];
        sM[tid] = fmaxf(t + se1b[tid], 0.f);
    }
    __syncthreads();
    float gbv = gb[0];
    for (int c = tid; c < CC; c += 256) {
        float s2 = 0.f;
        #pragma unroll
        for (int m = 0; m < SEM; ++m) s2 = fmaf(sM[m], se2w[c * SEM + m], s2);
        s2 += se2b[c];
        float wcw = 1.f / (1.f + __expf(-s2));
        float inv = gamma[c] * rsqrtf(var[c] + BN_EPS);
        float A = wcw * Ww[c] * inv;
        Ac[b * CC + c] = A;
        Dc[b * CC + c] = wcw * ((Wb[c] - mean[c]) * inv + beta[c]) + A * gbv;
    }
}

// ---------------- K3: rank-1 softmax (exp2, no-max) ----------------
// grid = 1024 blocks: 16 rows each, 4 per wave. Biases already applied.
__global__ __launch_bounds__(256) void k3(
    const float* __restrict__ gx, const float* __restrict__ tx,
    const float* __restrict__ px, float* __restrict__ y)
{
    __shared__ float smem[4096];
    int tid = threadIdx.x;
    float* spx = smem;           // 2048
    float* sgx = smem + 2048;    // 2048
    int b  = blockIdx.x >> 7;
    int i0 = (blockIdx.x & 127) << 4;
    {
        const float4* pxr = reinterpret_cast<const float4*>(px + (size_t)b * NN);
        const float4* gxr = reinterpret_cast<const float4*>(gx + (size_t)b * NN);
        float4* spx4 = reinterpret_cast<float4*>(spx);
        float4* sgx4 = reinterpret_cast<float4*>(sgx);
        #pragma unroll
        for (int w = 0; w < 2; ++w) {
            int idx = w * 256 + tid;
            spx4[idx] = pxr[idx];
            sgx4[idx] = gxr[idx];
        }
    }
    __syncthreads();

    int wave = tid >> 6, lane = tid & 63;
    int r0 = i0 + wave * 4;
    float t0 = tx[b * NN + r0 + 0] * LOG2E;
    float t1 = tx[b * NN + r0 + 1] * LOG2E;
    float t2 = tx[b * NN + r0 + 2] * LOG2E;
    float t3 = tx[b * NN + r0 + 3] * LOG2E;
    float s0 = 0.f, g0 = 0.f, s1 = 0.f, g1 = 0.f;
    float s2 = 0.f, g2 = 0.f, s3 = 0.f, g3 = 0.f;
    const float2* spx2 = reinterpret_cast<const float2*>(spx);
    const float2* sgx2 = reinterpret_cast<const float2*>(sgx);
    #pragma unroll 4
    for (int it = 0; it < 16; ++it) {
        int jj = it * 64 + lane;
        float2 xv = spx2[jj];
        float2 gv = sgx2[jj];
        float e0a = exp2f(fminf(t0 * xv.x, 115.f)), e0b = exp2f(fminf(t0 * xv.y, 115.f));
        float e1a = exp2f(fminf(t1 * xv.x, 115.f)), e1b = exp2f(fminf(t1 * xv.y, 115.f));
        float e2a = exp2f(fminf(t2 * xv.x, 115.f)), e2b = exp2f(fminf(t2 * xv.y, 115.f));
        float e3a = exp2f(fminf(t3 * xv.x, 115.f)), e3b = exp2f(fminf(t3 * xv.y, 115.f));
        s0 += e0a + e0b; g0 = fmaf(e0a, gv.x, fmaf(e0b, gv.y, g0));
        s1 += e1a + e1b; g1 = fmaf(e1a, gv.x, fmaf(e1b, gv.y, g1));
        s2 += e2a + e2b; g2 = fmaf(e2a, gv.x, fmaf(e2b, gv.y, g2));
        s3 += e3a + e3b; g3 = fmaf(e3a, gv.x, fmaf(e3b, gv.y, g3));
    }
    for (int o = 32; o > 0; o >>= 1) {
        s0 += __shfl_down(s0, o); g0 += __shfl_down(g0, o);
        s1 += __shfl_down(s1, o); g1 += __shfl_down(g1, o);
        s2 += __shfl_down(s2, o); g2 += __shfl_down(g2, o);
        s3 += __shfl_down(s3, o); g3 += __shfl_down(g3, o);
    }
    if (lane == 0) {
        y[b * NN + r0 + 0] = g0 / s0;
        y[b * NN + r0 + 1] = g1 / s1;
        y[b * NN + r0 + 2] = g2 / s2;
        y[b * NN + r0 + 3] = g3 / s3;
    }
}

// ---------------- K4: epilogue out = A*y + D + x ----------------
// grid = 4096 blocks: one (b,c) row each; thread: 2 float4.
__global__ __launch_bounds__(256) void k4(
    const float* __restrict__ x, const float* __restrict__ y,
    const float* __restrict__ Ac, const float* __restrict__ Dc,
    float* __restrict__ out)
{
    int bc = blockIdx.x;
    int b = bc >> 9;
    float a = Ac[bc], d = Dc[bc];
    const float4* x4 = reinterpret_cast<const float4*>(x) + (size_t)bc * (NN / 4);
    const float4* y4 = reinterpret_cast<const float4*>(y) + (size_t)b * (NN / 4);
    float4* o4 = reinterpret_cast<float4*>(out) + (size_t)bc * (NN / 4);
    int tid = threadIdx.x;
    #pragma unroll
    for (int k = 0; k < 2; ++k) {
        int idx = k * 256 + tid;
        float4 xv = x4[idx], yv = y4[idx], ov;
        ov.x = fmaf(a, yv.x, d) + xv.x;
        ov.y = fmaf(a, yv.y, d) + xv.y;
        ov.z = fmaf(a, yv.z, d) + xv.z;
        ov.w = fmaf(a, yv.w, d) + xv.w;
        o4[idx] = ov;
    }
}

extern "C" void kernel_launch(void* const* d_in, const int* in_sizes, int n_in,
                              void* d_out, int out_size, void* d_ws, size_t ws_size,
                              hipStream_t stream) {
    const float* x    = (const float*)d_in[0];
    const float* gw   = (const float*)d_in[1];
    const float* gb   = (const float*)d_in[2];
    const float* tw   = (const float*)d_in[3];
    const float* tb   = (const float*)d_in[4];
    const float* pw   = (const float*)d_in[5];
    const float* pb   = (const float*)d_in[6];
    const float* Ww   = (const float*)d_in[7];
    const float* Wb   = (const float*)d_in[8];
    const float* gam  = (const float*)d_in[9];
    const float* bet  = (const float*)d_in[10];
    const float* mu   = (const float*)d_in[11];
    const float* var  = (const float*)d_in[12];
    const float* se1w = (const float*)d_in[13];
    const float* se1b = (const float*)d_in[14];
    const float* se2w = (const float*)d_in[15];
    const float* se2b = (const float*)d_in[16];

    float* ws   = (float*)d_ws;
    float* pp   = ws; ws += 3 * (size_t)KARR;
    float* avgp = ws; ws += BB * CC * 8;
    float* gx   = ws; ws += BB * NN;
    float* tx   = ws; ws += BB * NN;
    float* px   = ws; ws += BB * NN;
    float* y    = ws; ws += BB * NN;
    float* Ac   = ws; ws += BB * CC;
    float* Dc   = ws; ws += BB * CC;
    float* out  = (float*)d_out;

    k1<<<1024, 256, 0, stream>>>(x, gw, tw, pw, pp, avgp);
    k2<<<200, 256, 0, stream>>>(pp, avgp, gb, tb, pb, se1w, se1b, se2w, se2b,
                                Ww, Wb, gam, bet, mu, var, gx, tx, px, Ac, Dc);
    k3<<<1024, 256, 0, stream>>>(gx, tx, px, y);
    k4<<<BB * CC, 256, 0, stream>>>(x, y, Ac, Dc, out);
}